// Round 3
// baseline (661.398 us; speedup 1.0000x reference)
//
#include <hip/hip_runtime.h>
#include <cstdint>
#include <cstddef>

typedef __attribute__((ext_vector_type(8))) short bf16x8;
typedef __attribute__((ext_vector_type(4))) float f32x4;

__device__ __forceinline__ ushort f2b(float f) {
    union { float f; uint32_t u; } v; v.f = f;
    uint32_t r = (v.u + 0x7fffu + ((v.u >> 16) & 1u)) >> 16;
    return (ushort)r;
}
__device__ __forceinline__ float b2f(ushort b) {
    union { uint32_t u; float f; } v; v.u = ((uint32_t)b) << 16;
    return v.f;
}

// direct global->LDS async copy, 16B per lane. LDS dest must be wave-uniform base.
__device__ __forceinline__ void gll16(const void* g, void* l) {
    __builtin_amdgcn_global_load_lds((const __attribute__((address_space(1))) void*)g,
                                     (__attribute__((address_space(3))) void*)l, 16, 0, 0);
}

// ================= CSR build: two-level bucket sort =================
__global__ __launch_bounds__(256) void hist_kernel(const int* __restrict__ rows,
                                                   int* __restrict__ bhist, int E, int nb) {
    __shared__ int h[512];
    for (int i = threadIdx.x; i < nb; i += 256) h[i] = 0;
    __syncthreads();
    int stride = gridDim.x * blockDim.x;
    for (int e = blockIdx.x * blockDim.x + threadIdx.x; e < E; e += stride)
        atomicAdd(&h[rows[e] >> 7], 1);
    __syncthreads();
    for (int i = threadIdx.x; i < nb; i += 256)
        if (h[i]) atomicAdd(&bhist[i], h[i]);
}

__global__ __launch_bounds__(512) void scan512(const int* __restrict__ bhist,
                                               int* __restrict__ boff, int* __restrict__ gcur,
                                               int* __restrict__ rp, int nb, int E, int N) {
    __shared__ int sm[512];
    int v = ((int)threadIdx.x < nb) ? bhist[threadIdx.x] : 0;
    sm[threadIdx.x] = v;
    __syncthreads();
    for (int off = 1; off < 512; off <<= 1) {
        int t = ((int)threadIdx.x >= off) ? sm[threadIdx.x - off] : 0;
        __syncthreads();
        sm[threadIdx.x] += t;
        __syncthreads();
    }
    if ((int)threadIdx.x < nb) {
        int e0 = sm[threadIdx.x] - v;
        boff[threadIdx.x] = e0;
        gcur[threadIdx.x] = e0;
    }
    if (threadIdx.x == 0) { boff[nb] = E; rp[N] = E; }
}

__global__ __launch_bounds__(256) void binpass(const int* __restrict__ rows,
                                               const int* __restrict__ cols,
                                               const float* __restrict__ avals,
                                               int* __restrict__ gcur,
                                               uint2* __restrict__ tmp, int E, int nb) {
    __shared__ int hist[512];
    __shared__ int base[512];
    int e0 = blockIdx.x * 4096;
    int nE = min(4096, E - e0);
    for (int i = threadIdx.x; i < nb; i += 256) hist[i] = 0;
    __syncthreads();
    for (int i = threadIdx.x; i < nE; i += 256)
        atomicAdd(&hist[rows[e0 + i] >> 7], 1);
    __syncthreads();
    for (int i = threadIdx.x; i < nb; i += 256) {
        int c = hist[i];
        if (c) base[i] = atomicAdd(&gcur[i], c);
        hist[i] = 0;
    }
    __syncthreads();
    for (int i = threadIdx.x; i < nE; i += 256) {
        int r = rows[e0 + i];
        int b = r >> 7;
        int loc = atomicAdd(&hist[b], 1);
        uint2 t;
        t.x = ((uint32_t)r << 16) | (uint32_t)cols[e0 + i];
        t.y = __float_as_uint(avals[e0 + i]);
        tmp[base[b] + loc] = t;
    }
}

__global__ __launch_bounds__(256) void bucketpass(const uint2* __restrict__ tmp,
                                                  const int* __restrict__ boff,
                                                  int* __restrict__ rp,
                                                  int* __restrict__ col_s,
                                                  float* __restrict__ a_s, int N) {
    __shared__ int cnt[128];
    __shared__ int pre[128];
    int b = blockIdx.x;
    int r0 = b << 7;
    int nr = min(128, N - r0);
    int t0 = boff[b], t1 = boff[b + 1];
    if ((int)threadIdx.x < 128) cnt[threadIdx.x] = 0;
    __syncthreads();
    for (int i = t0 + (int)threadIdx.x; i < t1; i += 256)
        atomicAdd(&cnt[(tmp[i].x >> 16) - r0], 1);
    __syncthreads();
    if ((int)threadIdx.x < 128) pre[threadIdx.x] = cnt[threadIdx.x];
    __syncthreads();
    for (int off = 1; off < 128; off <<= 1) {
        int t = ((int)threadIdx.x >= off && (int)threadIdx.x < 128) ? pre[threadIdx.x - off] : 0;
        __syncthreads();
        if ((int)threadIdx.x < 128) pre[threadIdx.x] += t;
        __syncthreads();
    }
    if ((int)threadIdx.x < nr) {
        int ex = pre[threadIdx.x] - cnt[threadIdx.x];
        rp[r0 + threadIdx.x] = t0 + ex;
        cnt[threadIdx.x] = t0 + ex;
    }
    __syncthreads();
    for (int i = t0 + (int)threadIdx.x; i < t1; i += 256) {
        uint2 t = tmp[i];
        int lr = (int)(t.x >> 16) - r0;
        int pos = atomicAdd(&cnt[lr], 1);
        col_s[pos] = (int)(t.x & 0xffffu);
        a_s[pos] = __uint_as_float(t.y);
    }
}

// ---------------- weight prep: u0=W0^T v00, u1=W0^T v01, bp=W1 b0, cc={b0.v00, b0.v01} ----------------
__global__ __launch_bounds__(256) void wprep(const float* __restrict__ W0,
                                             const float* __restrict__ W1,
                                             const float* __restrict__ b0,
                                             const float* __restrict__ v00,
                                             const float* __restrict__ v01,
                                             float* __restrict__ u0,
                                             float* __restrict__ u1,
                                             float* __restrict__ bp,
                                             float* __restrict__ cc) {
    if (blockIdx.x == 0) {
        int c = threadIdx.x;
        for (int rep = 0; rep < 2; ++rep, c += 256) {
            float s0 = 0.f, s1 = 0.f;
            for (int r = 0; r < 256; ++r) {
                float w = W0[(size_t)r * 512 + c];   // coalesced across threads
                s0 += w * v00[r];
                s1 += w * v01[r];
            }
            u0[c] = s0;
            u1[c] = s1;
        }
    } else {
        int i = threadIdx.x;
        if (i < 128) {
            float s = 0.f;
            for (int k = 0; k < 256; ++k) s += W1[(size_t)i * 256 + k] * b0[k];
            bp[i] = s;
        } else if (i == 128) {
            float s = 0.f;
            for (int k = 0; k < 256; ++k) s += b0[k] * v00[k];
            cc[0] = s;
        } else if (i == 129) {
            float s = 0.f;
            for (int k = 0; k < 256; ++k) s += b0[k] * v01[k];
            cc[1] = s;
        }
    }
}

// ---------------- X fp32 -> bf16 convert + fused f1/f2 = X.u0 + c0, X.u1 + c1 ----------------
// 256 threads = 4 waves; each wave handles 2 rows (512 floats each, 2x float4 per lane).
__global__ __launch_bounds__(256) void convert_fx(const float* __restrict__ X,
                                                  const float* __restrict__ u0,
                                                  const float* __restrict__ u1,
                                                  const float* __restrict__ cc,
                                                  ushort* __restrict__ Xh,
                                                  float* __restrict__ f1,
                                                  float* __restrict__ f2, int N) {
    int w = threadIdx.x >> 6;
    int l = threadIdx.x & 63;
    const float4* U0 = (const float4*)u0;
    const float4* U1 = (const float4*)u1;
    float4 ua = U0[l * 2], ub = U0[l * 2 + 1];
    float4 va = U1[l * 2], vb = U1[l * 2 + 1];
    float c0 = cc[0], c1 = cc[1];
#pragma unroll
    for (int rr = 0; rr < 2; ++rr) {
        int row = blockIdx.x * 8 + w * 2 + rr;
        if (row >= N) return;
        const float4* Xr = (const float4*)(X + (size_t)row * 512);
        float4 x0 = Xr[l * 2], x1 = Xr[l * 2 + 1];
        ushort4 h0, h1;
        h0.x = f2b(x0.x); h0.y = f2b(x0.y); h0.z = f2b(x0.z); h0.w = f2b(x0.w);
        h1.x = f2b(x1.x); h1.y = f2b(x1.y); h1.z = f2b(x1.z); h1.w = f2b(x1.w);
        ushort4* Xo = (ushort4*)(Xh + (size_t)row * 512);
        Xo[l * 2] = h0;
        Xo[l * 2 + 1] = h1;
        float s1 = x0.x * ua.x + x0.y * ua.y + x0.z * ua.z + x0.w * ua.w
                 + x1.x * ub.x + x1.y * ub.y + x1.z * ub.z + x1.w * ub.w;
        float s2 = x0.x * va.x + x0.y * va.y + x0.z * va.z + x0.w * va.w
                 + x1.x * vb.x + x1.y * vb.y + x1.z * vb.z + x1.w * vb.w;
#pragma unroll
        for (int off = 32; off > 0; off >>= 1) {
            s1 += __shfl_xor(s1, off);
            s2 += __shfl_xor(s2, off);
        }
        if (l == 0) { f1[row] = s1 + c0; f2[row] = s2 + c1; }
    }
}

// W0 [256,512] -> Wt0h = W0^T bf16 [512,256]; W1 [128,256] -> W1h bf16.
__global__ __launch_bounds__(256) void prep_weights(const float* __restrict__ W0,
                                                    const float* __restrict__ W1,
                                                    ushort* __restrict__ W1h,
                                                    ushort* __restrict__ Wt0h) {
    int i = blockIdx.x * 256 + threadIdx.x;   // 0..32767
    float4 v = ((const float4*)W0)[i];
    ushort4 o;
    o.x = f2b(v.x); o.y = f2b(v.y); o.z = f2b(v.z); o.w = f2b(v.w);
    int r = (i * 4) >> 9;          // W0 row
    int c = (i * 4) & 511;         // W0 col (4 consecutive, same row)
    Wt0h[(size_t)(c + 0) * 256 + r] = o.x;
    Wt0h[(size_t)(c + 1) * 256 + r] = o.y;
    Wt0h[(size_t)(c + 2) * 256 + r] = o.z;
    Wt0h[(size_t)(c + 3) * 256 + r] = o.w;
    if (i < 8192) {
        float4 w = ((const float4*)W1)[i];
        ushort4 p;
        p.x = f2b(w.x); p.y = f2b(w.y); p.z = f2b(w.z); p.w = f2b(w.w);
        ((ushort4*)W1h)[i] = p;
    }
}

// ---------------- bf16 MFMA NT GEMM, global_load_lds staging ----------------
// C[M,Dout] = A[M,K] @ B[Dout,K]^T + bias.  A,B bf16 row-major, K%64==0, Dout%128==0.
// 128x128 tile, 256 threads = 4 waves (64x64 quadrant each), BK=64.
// LDS linear [128][64] ushort per matrix; 16B chunk at (row, c) stores global chunk
// (row, c ^ (row&7)) -> ds_read_b128 fragment reads are 2-way (free) instead of 8-way.
// Optional ChT: bf16 store of C^T as [Dout, M] row-major.
__global__ __launch_bounds__(256) void gemm_bf16(const ushort* __restrict__ A,
                                                 const ushort* __restrict__ B,
                                                 const float* __restrict__ bias,
                                                 float* __restrict__ Cf,
                                                 ushort* __restrict__ Ch,
                                                 ushort* __restrict__ ChT,
                                                 int M, int K, int Dout) {
    __shared__ ushort As[128 * 64];
    __shared__ ushort Bs[128 * 64];
    int bm = blockIdx.y * 128, bn = blockIdx.x * 128;
    int tid = threadIdx.x;
    int w = tid >> 6, l = tid & 63;
    int wm = (w & 1) * 64, wn = (w >> 1) * 64;
    int lm = l & 15, quad = l >> 4;
    int wslot = tid & 192;               // wave-uniform slot base (0,64,128,192)

    f32x4 acc[4][4] = {};

    for (int k0 = 0; k0 < K; k0 += 64) {
#pragma unroll
        for (int it = 0; it < 4; ++it) {
            int slot = it * 256 + tid;       // 0..1023: one 16B chunk each
            int row = slot >> 3;             // 0..127
            int qg = ((slot & 7) ^ (row & 7)) * 8;   // pre-swizzled source chunk
            int ga = bm + row; if (ga > M - 1) ga = M - 1;
            gll16(A + (size_t)ga * K + k0 + qg, As + (size_t)(it * 256 + wslot) * 8);
            gll16(B + (size_t)(bn + row) * K + k0 + qg, Bs + (size_t)(it * 256 + wslot) * 8);
        }
        __syncthreads();
#pragma unroll
        for (int ks = 0; ks < 2; ++ks) {
            bf16x8 af[4], bfr[4];
#pragma unroll
            for (int i = 0; i < 4; ++i) {
                int r = wm + i * 16 + lm;
                af[i] = *(const bf16x8*)&As[r * 64 + (((ks * 4 + quad) ^ (r & 7)) * 8)];
            }
#pragma unroll
            for (int j = 0; j < 4; ++j) {
                int r = wn + j * 16 + lm;
                bfr[j] = *(const bf16x8*)&Bs[r * 64 + (((ks * 4 + quad) ^ (r & 7)) * 8)];
            }
#pragma unroll
            for (int i = 0; i < 4; ++i)
#pragma unroll
                for (int j = 0; j < 4; ++j)
                    acc[i][j] = __builtin_amdgcn_mfma_f32_16x16x32_bf16(af[i], bfr[j], acc[i][j], 0, 0, 0);
        }
        __syncthreads();
    }

    float bv[4] = {0.f, 0.f, 0.f, 0.f};
    if (bias) {
#pragma unroll
        for (int j = 0; j < 4; ++j) bv[j] = bias[bn + wn + j * 16 + lm];
    }
#pragma unroll
    for (int i = 0; i < 4; ++i) {
#pragma unroll
        for (int r = 0; r < 4; ++r) {
            int row = bm + wm + i * 16 + quad * 4 + r;
            if (row < M) {
#pragma unroll
                for (int j = 0; j < 4; ++j) {
                    int col = bn + wn + j * 16 + lm;
                    float v = acc[i][j][r] + bv[j];
                    if (Cf) Cf[(size_t)row * Dout + col] = v;
                    if (Ch) Ch[(size_t)row * Dout + col] = f2b(v);
                    if (ChT) ChT[(size_t)col * M + row] = f2b(v);
                }
            }
        }
    }
}

// ---------------- edge attention, single sweep ----------------
// Softmax is shift-invariant and sigmoid in (0,1) bounds exp <= e: no max pass needed.
// Stores unnormalized e; per-row 1/sum goes to rs[] and is applied in spmm.
__global__ __launch_bounds__(256) void att2_kernel(const int* __restrict__ rp,
                                                   const int* __restrict__ col_s,
                                                   const float* __restrict__ a_s,
                                                   const float* __restrict__ f1,
                                                   const float* __restrict__ f2,
                                                   float* __restrict__ att,
                                                   float* __restrict__ rs, int N) {
    int r = blockIdx.x * 4 + (threadIdx.x >> 6);
    if (r >= N) return;
    int lane = threadIdx.x & 63;
    int beg = rp[r], end = rp[r + 1];
    float fr = f1[r];
    float s = 0.f;
    for (int j = beg + lane; j < end; j += 64) {
        float x = a_s[j] * (fr + f2[col_s[j]]);
        float v = 1.f / (1.f + __expf(-x));
        float e = __expf(v);
        att[j] = e;
        s += e;
    }
#pragma unroll
    for (int off = 32; off > 0; off >>= 1) s += __shfl_xor(s, off);
    if (lane == 0) rs[r] = (end > beg) ? 1.f / s : 0.f;
}

// ---------------- SpMM d=128 (CSR gather, 16 lanes/row x 16B, fp32 accumulate) ----------------
// acc = (sum_e att[e]*H[col]) * rs[row] + bias; optional fused f1/f2 = acc . va/vb.
__global__ __launch_bounds__(256) void spmm128(const int* __restrict__ rp,
                                               const int* __restrict__ col_s,
                                               const float* __restrict__ att,
                                               const float* __restrict__ rs,
                                               const ushort* __restrict__ H,
                                               const float* __restrict__ bias,
                                               const float* __restrict__ va,
                                               const float* __restrict__ vb,
                                               float* __restrict__ f1,
                                               float* __restrict__ f2,
                                               ushort* __restrict__ Oh,
                                               float* __restrict__ Of, int N) {
    int r = blockIdx.x * 16 + (threadIdx.x >> 4);
    if (r >= N) return;
    int lane = threadIdx.x & 15;
    int beg = rp[r], end = rp[r + 1];
    float acc[8] = {0.f, 0.f, 0.f, 0.f, 0.f, 0.f, 0.f, 0.f};
    const uint4* H4 = (const uint4*)H;
#define FMA8(h, wgt) { \
        acc[0] += (wgt) * b2f((ushort)((h).x & 0xffffu)); \
        acc[1] += (wgt) * b2f((ushort)((h).x >> 16)); \
        acc[2] += (wgt) * b2f((ushort)((h).y & 0xffffu)); \
        acc[3] += (wgt) * b2f((ushort)((h).y >> 16)); \
        acc[4] += (wgt) * b2f((ushort)((h).z & 0xffffu)); \
        acc[5] += (wgt) * b2f((ushort)((h).z >> 16)); \
        acc[6] += (wgt) * b2f((ushort)((h).w & 0xffffu)); \
        acc[7] += (wgt) * b2f((ushort)((h).w >> 16)); }
    int j = beg;
    for (; j + 4 <= end; j += 4) {
        int c0 = col_s[j], c1 = col_s[j + 1], c2 = col_s[j + 2], c3 = col_s[j + 3];
        float w0 = att[j], w1 = att[j + 1], w2 = att[j + 2], w3 = att[j + 3];
        uint4 h0 = H4[(size_t)c0 * 16 + lane];
        uint4 h1 = H4[(size_t)c1 * 16 + lane];
        uint4 h2 = H4[(size_t)c2 * 16 + lane];
        uint4 h3 = H4[(size_t)c3 * 16 + lane];
        FMA8(h0, w0) FMA8(h1, w1) FMA8(h2, w2) FMA8(h3, w3)
    }
    for (; j < end; ++j) {
        uint4 h = H4[(size_t)col_s[j] * 16 + lane];
        float w0 = att[j];
        FMA8(h, w0)
    }
#undef FMA8
    float rsv = rs[r];
#pragma unroll
    for (int k = 0; k < 8; ++k) acc[k] *= rsv;
    if (bias) {
        const float4* b4 = (const float4*)(bias + lane * 8);
        float4 ba = b4[0], bb = b4[1];
        acc[0] += ba.x; acc[1] += ba.y; acc[2] += ba.z; acc[3] += ba.w;
        acc[4] += bb.x; acc[5] += bb.y; acc[6] += bb.z; acc[7] += bb.w;
    }
    if (va) {
        const float4* a4 = (const float4*)(va + lane * 8);
        const float4* c4 = (const float4*)(vb + lane * 8);
        float4 va0 = a4[0], va1 = a4[1], vb0 = c4[0], vb1 = c4[1];
        float p1 = acc[0] * va0.x + acc[1] * va0.y + acc[2] * va0.z + acc[3] * va0.w
                 + acc[4] * va1.x + acc[5] * va1.y + acc[6] * va1.z + acc[7] * va1.w;
        float p2 = acc[0] * vb0.x + acc[1] * vb0.y + acc[2] * vb0.z + acc[3] * vb0.w
                 + acc[4] * vb1.x + acc[5] * vb1.y + acc[6] * vb1.z + acc[7] * vb1.w;
#pragma unroll
        for (int off = 8; off > 0; off >>= 1) {
            p1 += __shfl_xor(p1, off);
            p2 += __shfl_xor(p2, off);
        }
        if (lane == 0) { f1[r] = p1; f2[r] = p2; }
    }
    if (Oh) {
        uint4 o;
        o.x = (uint32_t)f2b(acc[0]) | ((uint32_t)f2b(acc[1]) << 16);
        o.y = (uint32_t)f2b(acc[2]) | ((uint32_t)f2b(acc[3]) << 16);
        o.z = (uint32_t)f2b(acc[4]) | ((uint32_t)f2b(acc[5]) << 16);
        o.w = (uint32_t)f2b(acc[6]) | ((uint32_t)f2b(acc[7]) << 16);
        ((uint4*)Oh)[(size_t)r * 16 + lane] = o;
    }
    if (Of) {
        float4* O4 = (float4*)Of;
        O4[(size_t)r * 32 + lane * 2]     = make_float4(acc[0], acc[1], acc[2], acc[3]);
        O4[(size_t)r * 32 + lane * 2 + 1] = make_float4(acc[4], acc[5], acc[6], acc[7]);
    }
}

// ---------------- driver ----------------
// Algebra (all ops linear; softmax rows sum to 1 so bias commutes through spmm):
//   f1/f2 (layer0) = X.(W0^T v) + b0.v       (matvec — M0 never materialized)
//   Wp = W1@W0 [128,512], bp = W1 b0
//   P  = X@Wp^T + bp                         [N,128]  (== M0@W1^T)
//   M1 = spmm(att0, P) + b1                  [N,128]
//   H2 = spmm(att1, M1)                      [N,128]  (final_H)
//   out = spmm(att0, spmm(att1, H2)) @ Wp    [N,512]
extern "C" void kernel_launch(void* const* d_in, const int* in_sizes, int n_in,
                              void* d_out, int out_size, void* d_ws, size_t ws_size,
                              hipStream_t stream) {
    const float* X    = (const float*)d_in[0];
    const int*   erow = (const int*)d_in[1];
    const int*   ecol = (const int*)d_in[2];
    const float* aval = (const float*)d_in[3];
    const float* W0   = (const float*)d_in[4];
    const float* b0   = (const float*)d_in[5];
    const float* W1   = (const float*)d_in[6];
    const float* b1   = (const float*)d_in[7];
    const float* v00  = (const float*)d_in[8];
    const float* v01  = (const float*)d_in[9];
    const float* v10  = (const float*)d_in[10];
    const float* v11  = (const float*)d_in[11];

    const int D0 = 512, D1 = 256, D2 = 128;
    const int N = in_sizes[0] / D0;
    const int E = in_sizes[1];
    const int NB = (N + 127) / 128;
    float* out = (float*)d_out;

    char* ws = (char*)d_ws;
    size_t off = 0;
    auto alloc = [&](size_t bytes) {
        char* p = ws + off;
        off += (bytes + 255) & ~(size_t)255;
        return p;
    };
    ushort* Xh   = (ushort*)alloc((size_t)N * D0 * 2);
    ushort* Ph   = (ushort*)alloc((size_t)N * D2 * 2);  // P / S1
    ushort* M1h  = (ushort*)alloc((size_t)N * D2 * 2);
    ushort* H2h  = (ushort*)alloc((size_t)N * D2 * 2);
    ushort* S0h  = (ushort*)alloc((size_t)N * D2 * 2);
    ushort* W1h  = (ushort*)alloc((size_t)D2 * D1 * 2); // [128,256]
    ushort* Wt0h = (ushort*)alloc((size_t)D0 * D1 * 2); // W0^T [512,256]
    ushort* Wph  = (ushort*)alloc((size_t)D2 * D0 * 2); // Wp = W1@W0 [128,512]
    ushort* WfTh = (ushort*)alloc((size_t)D0 * D2 * 2); // Wp^T [512,128]
    float* att0  = (float*)alloc((size_t)E * 4);
    float* att1  = (float*)alloc((size_t)E * 4);
    float* a_s   = (float*)alloc((size_t)E * 4);
    float* f1    = (float*)alloc((size_t)N * 4);
    float* f2    = (float*)alloc((size_t)N * 4);
    float* rs0   = (float*)alloc((size_t)N * 4);
    float* rs1   = (float*)alloc((size_t)N * 4);
    float* u0    = (float*)alloc(512 * 4);
    float* u1    = (float*)alloc(512 * 4);
    float* bp    = (float*)alloc(128 * 4);
    float* cc    = (float*)alloc(2 * 4);
    int* rp      = (int*)alloc(((size_t)N + 1) * 4);
    int* col_s   = (int*)alloc((size_t)E * 4);
    uint2* tmp   = (uint2*)alloc((size_t)E * 8);
    int* bhist   = (int*)alloc(512 * 4);
    int* boff    = (int*)alloc(513 * 4);
    int* gcur    = (int*)alloc(512 * 4);

    // ---- CSR build ----
    hipMemsetAsync(bhist, 0, 512 * sizeof(int), stream);
    hist_kernel<<<256, 256, 0, stream>>>(erow, bhist, E, NB);
    scan512<<<1, 512, 0, stream>>>(bhist, boff, gcur, rp, NB, E, N);
    binpass<<<(E + 4095) / 4096, 256, 0, stream>>>(erow, ecol, aval, gcur, tmp, E, NB);
    bucketpass<<<NB, 256, 0, stream>>>(tmp, boff, rp, col_s, a_s, N);

    // ---- weight prep ----
    wprep<<<2, 256, 0, stream>>>(W0, W1, b0, v00, v01, u0, u1, bp, cc);
    prep_weights<<<128, 256, 0, stream>>>(W0, W1, W1h, Wt0h);

    // ---- X convert + fused layer-0 logits ----
    convert_fx<<<(N + 7) / 8, 256, 0, stream>>>(X, u0, u1, cc, Xh, f1, f2, N);

    // ---- fused weight: Wp[128,512] = W1@W0 = gemm_nt(W1h, Wt0h); also emit Wp^T ----
    gemm_bf16<<<dim3(4, 1), 256, 0, stream>>>(W1h, Wt0h, nullptr, nullptr, Wph, WfTh,
                                              D2, D1, D0);

    const int gy = (N + 127) / 128;
    const int agrid = (N + 3) / 4;
    const int sgrid = (N + 15) / 16;

    // ---- encoder ----
    att2_kernel<<<agrid, 256, 0, stream>>>(rp, col_s, a_s, f1, f2, att0, rs0, N);
    gemm_bf16<<<dim3(1, gy), 256, 0, stream>>>(Xh, Wph, bp, nullptr, Ph, nullptr,
                                               N, D0, D2);   // P = X@Wp^T + bp
    // M1 = spmm(att0,P)+b1, with fused f1/f2 = M1 . v10/v11 (fp32)
    spmm128<<<sgrid, 256, 0, stream>>>(rp, col_s, att0, rs0, Ph, b1, v10, v11, f1, f2,
                                       M1h, nullptr, N);
    att2_kernel<<<agrid, 256, 0, stream>>>(rp, col_s, a_s, f1, f2, att1, rs1, N);
    // H2 = final_H: bf16 for decoder + fp32 straight into output tail
    spmm128<<<sgrid, 256, 0, stream>>>(rp, col_s, att1, rs1, M1h, nullptr,
                                       nullptr, nullptr, nullptr, nullptr,
                                       H2h, out + (size_t)N * D0, N);

    // ---- decoder (fully commuted) ----
    spmm128<<<sgrid, 256, 0, stream>>>(rp, col_s, att1, rs1, H2h, nullptr,
                                       nullptr, nullptr, nullptr, nullptr,
                                       Ph, nullptr, N);   // S1
    spmm128<<<sgrid, 256, 0, stream>>>(rp, col_s, att0, rs0, Ph, nullptr,
                                       nullptr, nullptr, nullptr, nullptr,
                                       S0h, nullptr, N);  // S0
    gemm_bf16<<<dim3(D0 / 128, gy), 256, 0, stream>>>(S0h, WfTh, nullptr, out, nullptr,
                                                      nullptr, N, D2, D0);
}

// Round 4
// 612.648 us; speedup vs baseline: 1.0796x; 1.0796x over previous
//
#include <hip/hip_runtime.h>
#include <cstdint>
#include <cstddef>

typedef __attribute__((ext_vector_type(8))) short bf16x8;
typedef __attribute__((ext_vector_type(4))) float f32x4;

__device__ __forceinline__ ushort f2b(float f) {
    union { float f; uint32_t u; } v; v.f = f;
    uint32_t r = (v.u + 0x7fffu + ((v.u >> 16) & 1u)) >> 16;
    return (ushort)r;
}
__device__ __forceinline__ float b2f(ushort b) {
    union { uint32_t u; float f; } v; v.u = ((uint32_t)b) << 16;
    return v.f;
}
__device__ __forceinline__ uint32_t pack2(float a, float b) {
    return (uint32_t)f2b(a) | ((uint32_t)f2b(b) << 16);
}
__device__ __forceinline__ float dot4(float4 a, float4 b) {
    return a.x * b.x + a.y * b.y + a.z * b.z + a.w * b.w;
}

// direct global->LDS async copy, 16B per lane. LDS dest must be wave-uniform base.
__device__ __forceinline__ void gll16(const void* g, void* l) {
    __builtin_amdgcn_global_load_lds((const __attribute__((address_space(1))) void*)g,
                                     (__attribute__((address_space(3))) void*)l, 16, 0, 0);
}

// ================= CSR build: two-level bucket sort =================
__global__ __launch_bounds__(256) void hist_kernel(const int* __restrict__ rows,
                                                   int* __restrict__ bhist, int E, int nb) {
    __shared__ int h[512];
    for (int i = threadIdx.x; i < nb; i += 256) h[i] = 0;
    __syncthreads();
    int stride = gridDim.x * blockDim.x;
    for (int e = blockIdx.x * blockDim.x + threadIdx.x; e < E; e += stride)
        atomicAdd(&h[rows[e] >> 7], 1);
    __syncthreads();
    for (int i = threadIdx.x; i < nb; i += 256)
        if (h[i]) atomicAdd(&bhist[i], h[i]);
}

__global__ __launch_bounds__(512) void scan512(const int* __restrict__ bhist,
                                               int* __restrict__ boff, int* __restrict__ gcur,
                                               int* __restrict__ rp, int nb, int E, int N) {
    __shared__ int sm[512];
    int v = ((int)threadIdx.x < nb) ? bhist[threadIdx.x] : 0;
    sm[threadIdx.x] = v;
    __syncthreads();
    for (int off = 1; off < 512; off <<= 1) {
        int t = ((int)threadIdx.x >= off) ? sm[threadIdx.x - off] : 0;
        __syncthreads();
        sm[threadIdx.x] += t;
        __syncthreads();
    }
    if ((int)threadIdx.x < nb) {
        int e0 = sm[threadIdx.x] - v;
        boff[threadIdx.x] = e0;
        gcur[threadIdx.x] = e0;
    }
    if (threadIdx.x == 0) { boff[nb] = E; rp[N] = E; }
}

__global__ __launch_bounds__(256) void binpass(const int* __restrict__ rows,
                                               const int* __restrict__ cols,
                                               const float* __restrict__ avals,
                                               int* __restrict__ gcur,
                                               uint2* __restrict__ tmp, int E, int nb) {
    __shared__ int hist[512];
    __shared__ int base[512];
    int e0 = blockIdx.x * 4096;
    int nE = min(4096, E - e0);
    for (int i = threadIdx.x; i < nb; i += 256) hist[i] = 0;
    __syncthreads();
    for (int i = threadIdx.x; i < nE; i += 256)
        atomicAdd(&hist[rows[e0 + i] >> 7], 1);
    __syncthreads();
    for (int i = threadIdx.x; i < nb; i += 256) {
        int c = hist[i];
        if (c) base[i] = atomicAdd(&gcur[i], c);
        hist[i] = 0;
    }
    __syncthreads();
    for (int i = threadIdx.x; i < nE; i += 256) {
        int r = rows[e0 + i];
        int b = r >> 7;
        int loc = atomicAdd(&hist[b], 1);
        uint2 t;
        t.x = ((uint32_t)r << 16) | (uint32_t)cols[e0 + i];
        t.y = __float_as_uint(avals[e0 + i]);
        tmp[base[b] + loc] = t;
    }
}

__global__ __launch_bounds__(256) void bucketpass(const uint2* __restrict__ tmp,
                                                  const int* __restrict__ boff,
                                                  int* __restrict__ rp,
                                                  int* __restrict__ col_s,
                                                  float* __restrict__ a_s, int N) {
    __shared__ int cnt[128];
    __shared__ int pre[128];
    int b = blockIdx.x;
    int r0 = b << 7;
    int nr = min(128, N - r0);
    int t0 = boff[b], t1 = boff[b + 1];
    if ((int)threadIdx.x < 128) cnt[threadIdx.x] = 0;
    __syncthreads();
    for (int i = t0 + (int)threadIdx.x; i < t1; i += 256)
        atomicAdd(&cnt[(tmp[i].x >> 16) - r0], 1);
    __syncthreads();
    if ((int)threadIdx.x < 128) pre[threadIdx.x] = cnt[threadIdx.x];
    __syncthreads();
    for (int off = 1; off < 128; off <<= 1) {
        int t = ((int)threadIdx.x >= off && (int)threadIdx.x < 128) ? pre[threadIdx.x - off] : 0;
        __syncthreads();
        if ((int)threadIdx.x < 128) pre[threadIdx.x] += t;
        __syncthreads();
    }
    if ((int)threadIdx.x < nr) {
        int ex = pre[threadIdx.x] - cnt[threadIdx.x];
        rp[r0 + threadIdx.x] = t0 + ex;
        cnt[threadIdx.x] = t0 + ex;
    }
    __syncthreads();
    for (int i = t0 + (int)threadIdx.x; i < t1; i += 256) {
        uint2 t = tmp[i];
        int lr = (int)(t.x >> 16) - r0;
        int pos = atomicAdd(&cnt[lr], 1);
        col_s[pos] = (int)(t.x & 0xffffu);
        a_s[pos] = __uint_as_float(t.y);
    }
}

// ---------------- fused weight prep (one dispatch, 145 blocks) ----------------
// blocks 0..127 : W0 -> Wt0h (bf16 transpose), W1 -> W1h (bf16)
// blocks 128..143: u0 = W0^T v00, u1 = W0^T v01   (32 cols per block, 8-way row split)
// block 144     : bp = W1 b0, cc = {b0.v00, b0.v01}
__global__ __launch_bounds__(256) void prep_all(const float* __restrict__ W0,
                                                const float* __restrict__ W1,
                                                const float* __restrict__ b0,
                                                const float* __restrict__ v00,
                                                const float* __restrict__ v01,
                                                ushort* __restrict__ W1h,
                                                ushort* __restrict__ Wt0h,
                                                float* __restrict__ u0,
                                                float* __restrict__ u1,
                                                float* __restrict__ bp,
                                                float* __restrict__ cc) {
    __shared__ float su0[256];
    __shared__ float su1[256];
    int bid = blockIdx.x;
    int tid = threadIdx.x;
    if (bid < 128) {
        int i = bid * 256 + tid;   // 0..32767
        float4 v = ((const float4*)W0)[i];
        ushort4 o;
        o.x = f2b(v.x); o.y = f2b(v.y); o.z = f2b(v.z); o.w = f2b(v.w);
        int r = (i * 4) >> 9;          // W0 row
        int c = (i * 4) & 511;         // W0 col (4 consecutive, same row)
        Wt0h[(size_t)(c + 0) * 256 + r] = o.x;
        Wt0h[(size_t)(c + 1) * 256 + r] = o.y;
        Wt0h[(size_t)(c + 2) * 256 + r] = o.z;
        Wt0h[(size_t)(c + 3) * 256 + r] = o.w;
        if (i < 8192) {
            float4 w = ((const float4*)W1)[i];
            ushort4 p;
            p.x = f2b(w.x); p.y = f2b(w.y); p.z = f2b(w.z); p.w = f2b(w.w);
            ((ushort4*)W1h)[i] = p;
        }
    } else if (bid < 144) {
        int ci = tid & 31;
        int rl = tid >> 5;                       // 0..7
        int c = (bid - 128) * 32 + ci;           // 0..511
        float s0 = 0.f, s1 = 0.f;
        for (int r = rl; r < 256; r += 8) {
            float w = W0[(size_t)r * 512 + c];   // coalesced per 32-lane group
            s0 += w * v00[r];
            s1 += w * v01[r];
        }
        su0[tid] = s0;
        su1[tid] = s1;
        __syncthreads();
        if (tid < 32) {
            float a = 0.f, b = 0.f;
            for (int g = 0; g < 8; ++g) { a += su0[g * 32 + tid]; b += su1[g * 32 + tid]; }
            u0[c] = a;
            u1[c] = b;
        }
    } else {
        int i = tid;
        if (i < 128) {
            float s = 0.f;
            for (int k = 0; k < 256; ++k) s += W1[(size_t)i * 256 + k] * b0[k];
            bp[i] = s;
        } else if (i == 128) {
            float s = 0.f;
            for (int k = 0; k < 256; ++k) s += b0[k] * v00[k];
            cc[0] = s;
        } else if (i == 129) {
            float s = 0.f;
            for (int k = 0; k < 256; ++k) s += b0[k] * v01[k];
            cc[1] = s;
        }
    }
}

// ---------------- bf16 MFMA NT GEMM, global_load_lds staging ----------------
// C[M,Dout] = A[M,K] @ B[Dout,K]^T + bias.  A,B bf16 row-major, K%64==0, Dout%128==0.
// 128x128 tile, 256 threads = 4 waves (64x64 quadrant each), BK=64.
// LDS linear [128][64] ushort; chunk c of row r stores global chunk c^(r&7).
__global__ __launch_bounds__(256) void gemm_bf16(const ushort* __restrict__ A,
                                                 const ushort* __restrict__ B,
                                                 const float* __restrict__ bias,
                                                 float* __restrict__ Cf,
                                                 ushort* __restrict__ Ch,
                                                 ushort* __restrict__ ChT,
                                                 int M, int K, int Dout) {
    __shared__ ushort As[128 * 64];
    __shared__ ushort Bs[128 * 64];
    int bm = blockIdx.y * 128, bn = blockIdx.x * 128;
    int tid = threadIdx.x;
    int w = tid >> 6, l = tid & 63;
    int wm = (w & 1) * 64, wn = (w >> 1) * 64;
    int lm = l & 15, quad = l >> 4;
    int wslot = tid & 192;               // wave-uniform slot base

    f32x4 acc[4][4] = {};

    for (int k0 = 0; k0 < K; k0 += 64) {
#pragma unroll
        for (int it = 0; it < 4; ++it) {
            int slot = it * 256 + tid;       // 0..1023: one 16B chunk each
            int row = slot >> 3;             // 0..127
            int qg = ((slot & 7) ^ (row & 7)) * 8;   // pre-swizzled source chunk
            int ga = bm + row; if (ga > M - 1) ga = M - 1;
            gll16(A + (size_t)ga * K + k0 + qg, As + (size_t)(it * 256 + wslot) * 8);
            gll16(B + (size_t)(bn + row) * K + k0 + qg, Bs + (size_t)(it * 256 + wslot) * 8);
        }
        __syncthreads();
#pragma unroll
        for (int ks = 0; ks < 2; ++ks) {
            bf16x8 af[4], bfr[4];
#pragma unroll
            for (int i = 0; i < 4; ++i) {
                int r = wm + i * 16 + lm;
                af[i] = *(const bf16x8*)&As[r * 64 + (((ks * 4 + quad) ^ (r & 7)) * 8)];
            }
#pragma unroll
            for (int j = 0; j < 4; ++j) {
                int r = wn + j * 16 + lm;
                bfr[j] = *(const bf16x8*)&Bs[r * 64 + (((ks * 4 + quad) ^ (r & 7)) * 8)];
            }
#pragma unroll
            for (int i = 0; i < 4; ++i)
#pragma unroll
                for (int j = 0; j < 4; ++j)
                    acc[i][j] = __builtin_amdgcn_mfma_f32_16x16x32_bf16(af[i], bfr[j], acc[i][j], 0, 0, 0);
        }
        __syncthreads();
    }

    float bv[4] = {0.f, 0.f, 0.f, 0.f};
    if (bias) {
#pragma unroll
        for (int j = 0; j < 4; ++j) bv[j] = bias[bn + wn + j * 16 + lm];
    }
#pragma unroll
    for (int i = 0; i < 4; ++i) {
#pragma unroll
        for (int r = 0; r < 4; ++r) {
            int row = bm + wm + i * 16 + quad * 4 + r;
            if (row < M) {
#pragma unroll
                for (int j = 0; j < 4; ++j) {
                    int col = bn + wn + j * 16 + lm;
                    float v = acc[i][j][r] + bv[j];
                    if (Cf) Cf[(size_t)row * Dout + col] = v;
                    if (Ch) Ch[(size_t)row * Dout + col] = f2b(v);
                    if (ChT) ChT[(size_t)col * M + row] = f2b(v);
                }
            }
        }
    }
}

// ---------------- fused P-GEMM: Ph = X(fp32)@Wp^T + bp, f1/f2 = X.u0/u1 + cc ----------------
// Dout fixed = 128 (single block-column covers all K per row block), K = 512.
// A staged via registers (fp32 load -> bf16 convert -> swizzled ds_write_b128);
// B staged via gll16. f1/f2 accumulated in fp32 from the pre-quantization registers.
__global__ __launch_bounds__(256) void gemm_xp(const float* __restrict__ X,
                                               const ushort* __restrict__ B,
                                               const float* __restrict__ bp,
                                               const float* __restrict__ u0,
                                               const float* __restrict__ u1,
                                               const float* __restrict__ cc,
                                               ushort* __restrict__ Ph,
                                               float* __restrict__ f1,
                                               float* __restrict__ f2,
                                               int M, int K) {
    __shared__ ushort As[128 * 64];
    __shared__ ushort Bs[128 * 64];
    int bm = blockIdx.y * 128;
    int tid = threadIdx.x;
    int w = tid >> 6, l = tid & 63;
    int wm = (w & 1) * 64, wn = (w >> 1) * 64;
    int lm = l & 15, quad = l >> 4;
    int wslot = tid & 192;
    int ar = tid >> 2;          // staged row (and row+64)
    int aq = tid & 3;           // col quarter: cols aq*16 .. aq*16+15

    f32x4 acc[4][4] = {};
    float fA1 = 0.f, fA2 = 0.f, fB1 = 0.f, fB2 = 0.f;

    for (int k0 = 0; k0 < K; k0 += 64) {
        // B staging (async, issued first so it overlaps the A reg-work)
#pragma unroll
        for (int it = 0; it < 4; ++it) {
            int slot = it * 256 + tid;
            int row = slot >> 3;
            int qg = ((slot & 7) ^ (row & 7)) * 8;
            gll16(B + (size_t)row * K + k0 + qg, Bs + (size_t)(it * 256 + wslot) * 8);
        }
        // A: fp32 load -> f-accum -> bf16 pack -> swizzled LDS write (2 rows/thread)
        const float4* U0 = (const float4*)(u0 + k0 + aq * 16);
        const float4* U1 = (const float4*)(u1 + k0 + aq * 16);
        float4 ua0 = U0[0], ua1 = U0[1], ua2 = U0[2], ua3 = U0[3];
        float4 va0 = U1[0], va1 = U1[1], va2 = U1[2], va3 = U1[3];
#pragma unroll
        for (int rr = 0; rr < 2; ++rr) {
            int row = ar + rr * 64;
            int ga = bm + row; if (ga > M - 1) ga = M - 1;
            const float4* src = (const float4*)(X + (size_t)ga * K + k0 + aq * 16);
            float4 x0 = src[0], x1 = src[1], x2 = src[2], x3 = src[3];
            float s1 = dot4(x0, ua0) + dot4(x1, ua1) + dot4(x2, ua2) + dot4(x3, ua3);
            float s2 = dot4(x0, va0) + dot4(x1, va1) + dot4(x2, va2) + dot4(x3, va3);
            if (rr == 0) { fA1 += s1; fA2 += s2; } else { fB1 += s1; fB2 += s2; }
            uint4 pa, pb;
            pa.x = pack2(x0.x, x0.y); pa.y = pack2(x0.z, x0.w);
            pa.z = pack2(x1.x, x1.y); pa.w = pack2(x1.z, x1.w);
            pb.x = pack2(x2.x, x2.y); pb.y = pack2(x2.z, x2.w);
            pb.z = pack2(x3.x, x3.y); pb.w = pack2(x3.z, x3.w);
            int c0 = (aq * 2) ^ (row & 7);
            int c1 = (aq * 2 + 1) ^ (row & 7);
            *(uint4*)&As[row * 64 + c0 * 8] = pa;
            *(uint4*)&As[row * 64 + c1 * 8] = pb;
        }
        __syncthreads();
#pragma unroll
        for (int ks = 0; ks < 2; ++ks) {
            bf16x8 af[4], bfr[4];
#pragma unroll
            for (int i = 0; i < 4; ++i) {
                int r = wm + i * 16 + lm;
                af[i] = *(const bf16x8*)&As[r * 64 + (((ks * 4 + quad) ^ (r & 7)) * 8)];
            }
#pragma unroll
            for (int j = 0; j < 4; ++j) {
                int r = wn + j * 16 + lm;
                bfr[j] = *(const bf16x8*)&Bs[r * 64 + (((ks * 4 + quad) ^ (r & 7)) * 8)];
            }
#pragma unroll
            for (int i = 0; i < 4; ++i)
#pragma unroll
                for (int j = 0; j < 4; ++j)
                    acc[i][j] = __builtin_amdgcn_mfma_f32_16x16x32_bf16(af[i], bfr[j], acc[i][j], 0, 0, 0);
        }
        __syncthreads();
    }

    // f1/f2: reduce across the 4 threads (adjacent lanes) sharing each staged row
    fA1 += __shfl_xor(fA1, 1); fA1 += __shfl_xor(fA1, 2);
    fA2 += __shfl_xor(fA2, 1); fA2 += __shfl_xor(fA2, 2);
    fB1 += __shfl_xor(fB1, 1); fB1 += __shfl_xor(fB1, 2);
    fB2 += __shfl_xor(fB2, 1); fB2 += __shfl_xor(fB2, 2);
    if (aq == 0) {
        float c0 = cc[0], c1 = cc[1];
        int r0 = bm + ar;
        if (r0 < M) { f1[r0] = fA1 + c0; f2[r0] = fA2 + c1; }
        int r1 = r0 + 64;
        if (r1 < M) { f1[r1] = fB1 + c0; f2[r1] = fB2 + c1; }
    }

    float bv[4];
#pragma unroll
    for (int j = 0; j < 4; ++j) bv[j] = bp[wn + j * 16 + lm];
#pragma unroll
    for (int i = 0; i < 4; ++i) {
#pragma unroll
        for (int r = 0; r < 4; ++r) {
            int row = bm + wm + i * 16 + quad * 4 + r;
            if (row < M) {
#pragma unroll
                for (int j = 0; j < 4; ++j) {
                    int col = wn + j * 16 + lm;
                    Ph[(size_t)row * 128 + col] = f2b(acc[i][j][r] + bv[j]);
                }
            }
        }
    }
}

// ---------------- edge attention, single sweep ----------------
// Softmax is shift-invariant and sigmoid in (0,1) bounds exp <= e: no max pass needed.
// Stores unnormalized e; per-row 1/sum goes to rs[] and is applied in spmm.
__global__ __launch_bounds__(256) void att2_kernel(const int* __restrict__ rp,
                                                   const int* __restrict__ col_s,
                                                   const float* __restrict__ a_s,
                                                   const float* __restrict__ f1,
                                                   const float* __restrict__ f2,
                                                   float* __restrict__ att,
                                                   float* __restrict__ rs, int N) {
    int r = blockIdx.x * 4 + (threadIdx.x >> 6);
    if (r >= N) return;
    int lane = threadIdx.x & 63;
    int beg = rp[r], end = rp[r + 1];
    float fr = f1[r];
    float s = 0.f;
    for (int j = beg + lane; j < end; j += 64) {
        float x = a_s[j] * (fr + f2[col_s[j]]);
        float v = 1.f / (1.f + __expf(-x));
        float e = __expf(v);
        att[j] = e;
        s += e;
    }
#pragma unroll
    for (int off = 32; off > 0; off >>= 1) s += __shfl_xor(s, off);
    if (lane == 0) rs[r] = (end > beg) ? 1.f / s : 0.f;
}

// ---------------- SpMM d=128 (CSR gather, 16 lanes/row x 16B, fp32 accumulate) ----------------
// acc = (sum_e att[e]*H[col]) * rs[row] + bias; optional fused f1/f2 = acc . va/vb.
__global__ __launch_bounds__(256) void spmm128(const int* __restrict__ rp,
                                               const int* __restrict__ col_s,
                                               const float* __restrict__ att,
                                               const float* __restrict__ rs,
                                               const ushort* __restrict__ H,
                                               const float* __restrict__ bias,
                                               const float* __restrict__ va,
                                               const float* __restrict__ vb,
                                               float* __restrict__ f1,
                                               float* __restrict__ f2,
                                               ushort* __restrict__ Oh,
                                               float* __restrict__ Of, int N) {
    int r = blockIdx.x * 16 + (threadIdx.x >> 4);
    if (r >= N) return;
    int lane = threadIdx.x & 15;
    int beg = rp[r], end = rp[r + 1];
    float acc[8] = {0.f, 0.f, 0.f, 0.f, 0.f, 0.f, 0.f, 0.f};
    const uint4* H4 = (const uint4*)H;
#define FMA8(h, wgt) { \
        acc[0] += (wgt) * b2f((ushort)((h).x & 0xffffu)); \
        acc[1] += (wgt) * b2f((ushort)((h).x >> 16)); \
        acc[2] += (wgt) * b2f((ushort)((h).y & 0xffffu)); \
        acc[3] += (wgt) * b2f((ushort)((h).y >> 16)); \
        acc[4] += (wgt) * b2f((ushort)((h).z & 0xffffu)); \
        acc[5] += (wgt) * b2f((ushort)((h).z >> 16)); \
        acc[6] += (wgt) * b2f((ushort)((h).w & 0xffffu)); \
        acc[7] += (wgt) * b2f((ushort)((h).w >> 16)); }
    int j = beg;
    for (; j + 8 <= end; j += 8) {
        int c0 = col_s[j],     c1 = col_s[j + 1], c2 = col_s[j + 2], c3 = col_s[j + 3];
        int c4 = col_s[j + 4], c5 = col_s[j + 5], c6 = col_s[j + 6], c7 = col_s[j + 7];
        float w0 = att[j],     w1 = att[j + 1], w2 = att[j + 2], w3 = att[j + 3];
        float w4 = att[j + 4], w5 = att[j + 5], w6 = att[j + 6], w7 = att[j + 7];
        uint4 h0 = H4[(size_t)c0 * 16 + lane];
        uint4 h1 = H4[(size_t)c1 * 16 + lane];
        uint4 h2 = H4[(size_t)c2 * 16 + lane];
        uint4 h3 = H4[(size_t)c3 * 16 + lane];
        uint4 h4 = H4[(size_t)c4 * 16 + lane];
        uint4 h5 = H4[(size_t)c5 * 16 + lane];
        uint4 h6 = H4[(size_t)c6 * 16 + lane];
        uint4 h7 = H4[(size_t)c7 * 16 + lane];
        FMA8(h0, w0) FMA8(h1, w1) FMA8(h2, w2) FMA8(h3, w3)
        FMA8(h4, w4) FMA8(h5, w5) FMA8(h6, w6) FMA8(h7, w7)
    }
    for (; j + 4 <= end; j += 4) {
        int c0 = col_s[j], c1 = col_s[j + 1], c2 = col_s[j + 2], c3 = col_s[j + 3];
        float w0 = att[j], w1 = att[j + 1], w2 = att[j + 2], w3 = att[j + 3];
        uint4 h0 = H4[(size_t)c0 * 16 + lane];
        uint4 h1 = H4[(size_t)c1 * 16 + lane];
        uint4 h2 = H4[(size_t)c2 * 16 + lane];
        uint4 h3 = H4[(size_t)c3 * 16 + lane];
        FMA8(h0, w0) FMA8(h1, w1) FMA8(h2, w2) FMA8(h3, w3)
    }
    for (; j < end; ++j) {
        uint4 h = H4[(size_t)col_s[j] * 16 + lane];
        float w0 = att[j];
        FMA8(h, w0)
    }
#undef FMA8
    float rsv = rs[r];
#pragma unroll
    for (int k = 0; k < 8; ++k) acc[k] *= rsv;
    if (bias) {
        const float4* b4 = (const float4*)(bias + lane * 8);
        float4 ba = b4[0], bb = b4[1];
        acc[0] += ba.x; acc[1] += ba.y; acc[2] += ba.z; acc[3] += ba.w;
        acc[4] += bb.x; acc[5] += bb.y; acc[6] += bb.z; acc[7] += bb.w;
    }
    if (va) {
        const float4* a4 = (const float4*)(va + lane * 8);
        const float4* c4 = (const float4*)(vb + lane * 8);
        float4 va0 = a4[0], va1 = a4[1], vb0 = c4[0], vb1 = c4[1];
        float p1 = acc[0] * va0.x + acc[1] * va0.y + acc[2] * va0.z + acc[3] * va0.w
                 + acc[4] * va1.x + acc[5] * va1.y + acc[6] * va1.z + acc[7] * va1.w;
        float p2 = acc[0] * vb0.x + acc[1] * vb0.y + acc[2] * vb0.z + acc[3] * vb0.w
                 + acc[4] * vb1.x + acc[5] * vb1.y + acc[6] * vb1.z + acc[7] * vb1.w;
#pragma unroll
        for (int off = 8; off > 0; off >>= 1) {
            p1 += __shfl_xor(p1, off);
            p2 += __shfl_xor(p2, off);
        }
        if (lane == 0) { f1[r] = p1; f2[r] = p2; }
    }
    if (Oh) {
        uint4 o;
        o.x = (uint32_t)f2b(acc[0]) | ((uint32_t)f2b(acc[1]) << 16);
        o.y = (uint32_t)f2b(acc[2]) | ((uint32_t)f2b(acc[3]) << 16);
        o.z = (uint32_t)f2b(acc[4]) | ((uint32_t)f2b(acc[5]) << 16);
        o.w = (uint32_t)f2b(acc[6]) | ((uint32_t)f2b(acc[7]) << 16);
        ((uint4*)Oh)[(size_t)r * 16 + lane] = o;
    }
    if (Of) {
        float4* O4 = (float4*)Of;
        O4[(size_t)r * 32 + lane * 2]     = make_float4(acc[0], acc[1], acc[2], acc[3]);
        O4[(size_t)r * 32 + lane * 2 + 1] = make_float4(acc[4], acc[5], acc[6], acc[7]);
    }
}

// ---------------- driver ----------------
// Algebra (all ops linear; softmax rows sum to 1 so bias commutes through spmm):
//   f1/f2 (layer0) = X.(W0^T v) + b0.v       (fused into P-GEMM; M0 never materialized)
//   Wp = W1@W0 [128,512], bp = W1 b0
//   P  = X@Wp^T + bp                         [N,128]  (== M0@W1^T)
//   M1 = spmm(att0, P) + b1                  [N,128]
//   H2 = spmm(att1, M1)                      [N,128]  (final_H)
//   out = spmm(att0, spmm(att1, H2)) @ Wp    [N,512]
extern "C" void kernel_launch(void* const* d_in, const int* in_sizes, int n_in,
                              void* d_out, int out_size, void* d_ws, size_t ws_size,
                              hipStream_t stream) {
    const float* X    = (const float*)d_in[0];
    const int*   erow = (const int*)d_in[1];
    const int*   ecol = (const int*)d_in[2];
    const float* aval = (const float*)d_in[3];
    const float* W0   = (const float*)d_in[4];
    const float* b0   = (const float*)d_in[5];
    const float* W1   = (const float*)d_in[6];
    const float* b1   = (const float*)d_in[7];
    const float* v00  = (const float*)d_in[8];
    const float* v01  = (const float*)d_in[9];
    const float* v10  = (const float*)d_in[10];
    const float* v11  = (const float*)d_in[11];

    const int D0 = 512, D1 = 256, D2 = 128;
    const int N = in_sizes[0] / D0;
    const int E = in_sizes[1];
    const int NB = (N + 127) / 128;
    float* out = (float*)d_out;

    char* ws = (char*)d_ws;
    size_t off = 0;
    auto alloc = [&](size_t bytes) {
        char* p = ws + off;
        off += (bytes + 255) & ~(size_t)255;
        return p;
    };
    ushort* Ph   = (ushort*)alloc((size_t)N * D2 * 2);  // P / S1
    ushort* M1h  = (ushort*)alloc((size_t)N * D2 * 2);
    ushort* H2h  = (ushort*)alloc((size_t)N * D2 * 2);
    ushort* S0h  = (ushort*)alloc((size_t)N * D2 * 2);
    ushort* W1h  = (ushort*)alloc((size_t)D2 * D1 * 2); // [128,256]
    ushort* Wt0h = (ushort*)alloc((size_t)D0 * D1 * 2); // W0^T [512,256]
    ushort* Wph  = (ushort*)alloc((size_t)D2 * D0 * 2); // Wp = W1@W0 [128,512]
    ushort* WfTh = (ushort*)alloc((size_t)D0 * D2 * 2); // Wp^T [512,128]
    float* att0  = (float*)alloc((size_t)E * 4);
    float* att1  = (float*)alloc((size_t)E * 4);
    float* a_s   = (float*)alloc((size_t)E * 4);
    float* f1    = (float*)alloc((size_t)N * 4);
    float* f2    = (float*)alloc((size_t)N * 4);
    float* rs0   = (float*)alloc((size_t)N * 4);
    float* rs1   = (float*)alloc((size_t)N * 4);
    float* u0    = (float*)alloc(512 * 4);
    float* u1    = (float*)alloc(512 * 4);
    float* bp    = (float*)alloc(128 * 4);
    float* cc    = (float*)alloc(2 * 4);
    int* rp      = (int*)alloc(((size_t)N + 1) * 4);
    int* col_s   = (int*)alloc((size_t)E * 4);
    uint2* tmp   = (uint2*)alloc((size_t)E * 8);
    int* bhist   = (int*)alloc(512 * 4);
    int* boff    = (int*)alloc(513 * 4);
    int* gcur    = (int*)alloc(512 * 4);

    // ---- CSR build ----
    hipMemsetAsync(bhist, 0, 512 * sizeof(int), stream);
    hist_kernel<<<256, 256, 0, stream>>>(erow, bhist, E, NB);
    scan512<<<1, 512, 0, stream>>>(bhist, boff, gcur, rp, NB, E, N);
    binpass<<<(E + 4095) / 4096, 256, 0, stream>>>(erow, ecol, aval, gcur, tmp, E, NB);
    bucketpass<<<NB, 256, 0, stream>>>(tmp, boff, rp, col_s, a_s, N);

    // ---- weight prep (one dispatch) ----
    prep_all<<<145, 256, 0, stream>>>(W0, W1, b0, v00, v01, W1h, Wt0h, u0, u1, bp, cc);

    // ---- fused weight: Wp[128,512] = W1@W0 = gemm_nt(W1h, Wt0h); also emit Wp^T ----
    gemm_bf16<<<dim3(4, 1), 256, 0, stream>>>(W1h, Wt0h, nullptr, nullptr, Wph, WfTh,
                                              D2, D1, D0);

    const int gy = (N + 127) / 128;
    const int agrid = (N + 3) / 4;
    const int sgrid = (N + 15) / 16;

    // ---- encoder ----
    // P = X@Wp^T + bp, fused f1/f2 = X.u0/u1 + cc (fp32)
    gemm_xp<<<dim3(1, gy), 256, 0, stream>>>(X, Wph, bp, u0, u1, cc, Ph, f1, f2, N, D0);
    att2_kernel<<<agrid, 256, 0, stream>>>(rp, col_s, a_s, f1, f2, att0, rs0, N);
    // M1 = spmm(att0,P)+b1, with fused f1/f2 = M1 . v10/v11 (fp32)
    spmm128<<<sgrid, 256, 0, stream>>>(rp, col_s, att0, rs0, Ph, b1, v10, v11, f1, f2,
                                       M1h, nullptr, N);
    att2_kernel<<<agrid, 256, 0, stream>>>(rp, col_s, a_s, f1, f2, att1, rs1, N);
    // H2 = final_H: bf16 for decoder + fp32 straight into output tail
    spmm128<<<sgrid, 256, 0, stream>>>(rp, col_s, att1, rs1, M1h, nullptr,
                                       nullptr, nullptr, nullptr, nullptr,
                                       H2h, out + (size_t)N * D0, N);

    // ---- decoder (fully commuted) ----
    spmm128<<<sgrid, 256, 0, stream>>>(rp, col_s, att1, rs1, H2h, nullptr,
                                       nullptr, nullptr, nullptr, nullptr,
                                       Ph, nullptr, N);   // S1
    spmm128<<<sgrid, 256, 0, stream>>>(rp, col_s, att0, rs0, Ph, nullptr,
                                       nullptr, nullptr, nullptr, nullptr,
                                       S0h, nullptr, N);  // S0
    gemm_bf16<<<dim3(D0 / 128, gy), 256, 0, stream>>>(S0h, WfTh, nullptr, out, nullptr,
                                                      nullptr, N, D2, D0);
}

// Round 5
// 611.678 us; speedup vs baseline: 1.0813x; 1.0016x over previous
//
#include <hip/hip_runtime.h>
#include <cstdint>
#include <cstddef>

typedef __attribute__((ext_vector_type(8))) short bf16x8;
typedef __attribute__((ext_vector_type(4))) float f32x4;

__device__ __forceinline__ ushort f2b(float f) {
    union { float f; uint32_t u; } v; v.f = f;
    uint32_t r = (v.u + 0x7fffu + ((v.u >> 16) & 1u)) >> 16;
    return (ushort)r;
}
__device__ __forceinline__ float b2f(ushort b) {
    union { uint32_t u; float f; } v; v.u = ((uint32_t)b) << 16;
    return v.f;
}
__device__ __forceinline__ uint32_t pack2(float a, float b) {
    return (uint32_t)f2b(a) | ((uint32_t)f2b(b) << 16);
}
__device__ __forceinline__ float dot4(float4 a, float4 b) {
    return a.x * b.x + a.y * b.y + a.z * b.z + a.w * b.w;
}

// direct global->LDS async copy, 16B per lane. LDS dest must be wave-uniform base.
__device__ __forceinline__ void gll16(const void* g, void* l) {
    __builtin_amdgcn_global_load_lds((const __attribute__((address_space(1))) void*)g,
                                     (__attribute__((address_space(3))) void*)l, 16, 0, 0);
}

// ================= CSR build: two-level bucket sort =================
__global__ __launch_bounds__(256) void hist_kernel(const int* __restrict__ rows,
                                                   int* __restrict__ bhist, int E, int nb) {
    __shared__ int h[512];
    for (int i = threadIdx.x; i < nb; i += 256) h[i] = 0;
    __syncthreads();
    int stride = gridDim.x * blockDim.x;
    for (int e = blockIdx.x * blockDim.x + threadIdx.x; e < E; e += stride)
        atomicAdd(&h[rows[e] >> 7], 1);
    __syncthreads();
    for (int i = threadIdx.x; i < nb; i += 256)
        if (h[i]) atomicAdd(&bhist[i], h[i]);
}

__global__ __launch_bounds__(512) void scan512(const int* __restrict__ bhist,
                                               int* __restrict__ boff, int* __restrict__ gcur,
                                               int* __restrict__ rp, int nb, int E, int N) {
    __shared__ int sm[512];
    int v = ((int)threadIdx.x < nb) ? bhist[threadIdx.x] : 0;
    sm[threadIdx.x] = v;
    __syncthreads();
    for (int off = 1; off < 512; off <<= 1) {
        int t = ((int)threadIdx.x >= off) ? sm[threadIdx.x - off] : 0;
        __syncthreads();
        sm[threadIdx.x] += t;
        __syncthreads();
    }
    if ((int)threadIdx.x < nb) {
        int e0 = sm[threadIdx.x] - v;
        boff[threadIdx.x] = e0;
        gcur[threadIdx.x] = e0;
    }
    if (threadIdx.x == 0) { boff[nb] = E; rp[N] = E; }
}

__global__ __launch_bounds__(256) void binpass(const int* __restrict__ rows,
                                               const int* __restrict__ cols,
                                               const float* __restrict__ avals,
                                               int* __restrict__ gcur,
                                               uint2* __restrict__ tmp, int E, int nb) {
    __shared__ int hist[512];
    __shared__ int base[512];
    int e0 = blockIdx.x * 4096;
    int nE = min(4096, E - e0);
    for (int i = threadIdx.x; i < nb; i += 256) hist[i] = 0;
    __syncthreads();
    for (int i = threadIdx.x; i < nE; i += 256)
        atomicAdd(&hist[rows[e0 + i] >> 7], 1);
    __syncthreads();
    for (int i = threadIdx.x; i < nb; i += 256) {
        int c = hist[i];
        if (c) base[i] = atomicAdd(&gcur[i], c);
        hist[i] = 0;
    }
    __syncthreads();
    for (int i = threadIdx.x; i < nE; i += 256) {
        int r = rows[e0 + i];
        int b = r >> 7;
        int loc = atomicAdd(&hist[b], 1);
        uint2 t;
        t.x = ((uint32_t)r << 16) | (uint32_t)cols[e0 + i];
        t.y = __float_as_uint(avals[e0 + i]);
        tmp[base[b] + loc] = t;
    }
}

__global__ __launch_bounds__(256) void bucketpass(const uint2* __restrict__ tmp,
                                                  const int* __restrict__ boff,
                                                  int* __restrict__ rp,
                                                  int* __restrict__ col_s,
                                                  float* __restrict__ a_s, int N) {
    __shared__ int cnt[128];
    __shared__ int pre[128];
    int b = blockIdx.x;
    int r0 = b << 7;
    int nr = min(128, N - r0);
    int t0 = boff[b], t1 = boff[b + 1];
    if ((int)threadIdx.x < 128) cnt[threadIdx.x] = 0;
    __syncthreads();
    for (int i = t0 + (int)threadIdx.x; i < t1; i += 256)
        atomicAdd(&cnt[(tmp[i].x >> 16) - r0], 1);
    __syncthreads();
    if ((int)threadIdx.x < 128) pre[threadIdx.x] = cnt[threadIdx.x];
    __syncthreads();
    for (int off = 1; off < 128; off <<= 1) {
        int t = ((int)threadIdx.x >= off && (int)threadIdx.x < 128) ? pre[threadIdx.x - off] : 0;
        __syncthreads();
        if ((int)threadIdx.x < 128) pre[threadIdx.x] += t;
        __syncthreads();
    }
    if ((int)threadIdx.x < nr) {
        int ex = pre[threadIdx.x] - cnt[threadIdx.x];
        rp[r0 + threadIdx.x] = t0 + ex;
        cnt[threadIdx.x] = t0 + ex;
    }
    __syncthreads();
    for (int i = t0 + (int)threadIdx.x; i < t1; i += 256) {
        uint2 t = tmp[i];
        int lr = (int)(t.x >> 16) - r0;
        int pos = atomicAdd(&cnt[lr], 1);
        col_s[pos] = (int)(t.x & 0xffffu);
        a_s[pos] = __uint_as_float(t.y);
    }
}

// ---------------- fused weight prep (one dispatch, 145 blocks) ----------------
__global__ __launch_bounds__(256) void prep_all(const float* __restrict__ W0,
                                                const float* __restrict__ W1,
                                                const float* __restrict__ b0,
                                                const float* __restrict__ v00,
                                                const float* __restrict__ v01,
                                                ushort* __restrict__ W1h,
                                                ushort* __restrict__ Wt0h,
                                                float* __restrict__ u0,
                                                float* __restrict__ u1,
                                                float* __restrict__ bp,
                                                float* __restrict__ cc) {
    __shared__ float su0[256];
    __shared__ float su1[256];
    int bid = blockIdx.x;
    int tid = threadIdx.x;
    if (bid < 128) {
        int i = bid * 256 + tid;   // 0..32767
        float4 v = ((const float4*)W0)[i];
        ushort4 o;
        o.x = f2b(v.x); o.y = f2b(v.y); o.z = f2b(v.z); o.w = f2b(v.w);
        int r = (i * 4) >> 9;          // W0 row
        int c = (i * 4) & 511;         // W0 col (4 consecutive, same row)
        Wt0h[(size_t)(c + 0) * 256 + r] = o.x;
        Wt0h[(size_t)(c + 1) * 256 + r] = o.y;
        Wt0h[(size_t)(c + 2) * 256 + r] = o.z;
        Wt0h[(size_t)(c + 3) * 256 + r] = o.w;
        if (i < 8192) {
            float4 w = ((const float4*)W1)[i];
            ushort4 p;
            p.x = f2b(w.x); p.y = f2b(w.y); p.z = f2b(w.z); p.w = f2b(w.w);
            ((ushort4*)W1h)[i] = p;
        }
    } else if (bid < 144) {
        int ci = tid & 31;
        int rl = tid >> 5;                       // 0..7
        int c = (bid - 128) * 32 + ci;           // 0..511
        float s0 = 0.f, s1 = 0.f;
        for (int r = rl; r < 256; r += 8) {
            float w = W0[(size_t)r * 512 + c];   // coalesced per 32-lane group
            s0 += w * v00[r];
            s1 += w * v01[r];
        }
        su0[tid] = s0;
        su1[tid] = s1;
        __syncthreads();
        if (tid < 32) {
            float a = 0.f, b = 0.f;
            for (int g = 0; g < 8; ++g) { a += su0[g * 32 + tid]; b += su1[g * 32 + tid]; }
            u0[c] = a;
            u1[c] = b;
        }
    } else {
        int i = tid;
        if (i < 128) {
            float s = 0.f;
            for (int k = 0; k < 256; ++k) s += W1[(size_t)i * 256 + k] * b0[k];
            bp[i] = s;
        } else if (i == 128) {
            float s = 0.f;
            for (int k = 0; k < 256; ++k) s += b0[k] * v00[k];
            cc[0] = s;
        } else if (i == 129) {
            float s = 0.f;
            for (int k = 0; k < 256; ++k) s += b0[k] * v01[k];
            cc[1] = s;
        }
    }
}

// ---------------- bf16 MFMA NT GEMM, global_load_lds staging ----------------
__global__ __launch_bounds__(256) void gemm_bf16(const ushort* __restrict__ A,
                                                 const ushort* __restrict__ B,
                                                 const float* __restrict__ bias,
                                                 float* __restrict__ Cf,
                                                 ushort* __restrict__ Ch,
                                                 ushort* __restrict__ ChT,
                                                 int M, int K, int Dout) {
    __shared__ ushort As[128 * 64];
    __shared__ ushort Bs[128 * 64];
    int bm = blockIdx.y * 128, bn = blockIdx.x * 128;
    int tid = threadIdx.x;
    int w = tid >> 6, l = tid & 63;
    int wm = (w & 1) * 64, wn = (w >> 1) * 64;
    int lm = l & 15, quad = l >> 4;
    int wslot = tid & 192;               // wave-uniform slot base

    f32x4 acc[4][4] = {};

    for (int k0 = 0; k0 < K; k0 += 64) {
#pragma unroll
        for (int it = 0; it < 4; ++it) {
            int slot = it * 256 + tid;       // 0..1023: one 16B chunk each
            int row = slot >> 3;             // 0..127
            int qg = ((slot & 7) ^ (row & 7)) * 8;   // pre-swizzled source chunk
            int ga = bm + row; if (ga > M - 1) ga = M - 1;
            gll16(A + (size_t)ga * K + k0 + qg, As + (size_t)(it * 256 + wslot) * 8);
            gll16(B + (size_t)(bn + row) * K + k0 + qg, Bs + (size_t)(it * 256 + wslot) * 8);
        }
        __syncthreads();
#pragma unroll
        for (int ks = 0; ks < 2; ++ks) {
            bf16x8 af[4], bfr[4];
#pragma unroll
            for (int i = 0; i < 4; ++i) {
                int r = wm + i * 16 + lm;
                af[i] = *(const bf16x8*)&As[r * 64 + (((ks * 4 + quad) ^ (r & 7)) * 8)];
            }
#pragma unroll
            for (int j = 0; j < 4; ++j) {
                int r = wn + j * 16 + lm;
                bfr[j] = *(const bf16x8*)&Bs[r * 64 + (((ks * 4 + quad) ^ (r & 7)) * 8)];
            }
#pragma unroll
            for (int i = 0; i < 4; ++i)
#pragma unroll
                for (int j = 0; j < 4; ++j)
                    acc[i][j] = __builtin_amdgcn_mfma_f32_16x16x32_bf16(af[i], bfr[j], acc[i][j], 0, 0, 0);
        }
        __syncthreads();
    }

    float bv[4] = {0.f, 0.f, 0.f, 0.f};
    if (bias) {
#pragma unroll
        for (int j = 0; j < 4; ++j) bv[j] = bias[bn + wn + j * 16 + lm];
    }
#pragma unroll
    for (int i = 0; i < 4; ++i) {
#pragma unroll
        for (int r = 0; r < 4; ++r) {
            int row = bm + wm + i * 16 + quad * 4 + r;
            if (row < M) {
#pragma unroll
                for (int j = 0; j < 4; ++j) {
                    int col = bn + wn + j * 16 + lm;
                    float v = acc[i][j][r] + bv[j];
                    if (Cf) Cf[(size_t)row * Dout + col] = v;
                    if (Ch) Ch[(size_t)row * Dout + col] = f2b(v);
                    if (ChT) ChT[(size_t)col * M + row] = f2b(v);
                }
            }
        }
    }
}

// ---------------- fused P-GEMM: Ph = X(fp32)@Wp^T + bp, f1/f2 = X.u0/u1 + cc ----------------
__global__ __launch_bounds__(256) void gemm_xp(const float* __restrict__ X,
                                               const ushort* __restrict__ B,
                                               const float* __restrict__ bp,
                                               const float* __restrict__ u0,
                                               const float* __restrict__ u1,
                                               const float* __restrict__ cc,
                                               ushort* __restrict__ Ph,
                                               float* __restrict__ f1,
                                               float* __restrict__ f2,
                                               int M, int K) {
    __shared__ ushort As[128 * 64];
    __shared__ ushort Bs[128 * 64];
    int bm = blockIdx.y * 128;
    int tid = threadIdx.x;
    int w = tid >> 6, l = tid & 63;
    int wm = (w & 1) * 64, wn = (w >> 1) * 64;
    int lm = l & 15, quad = l >> 4;
    int wslot = tid & 192;
    int ar = tid >> 2;          // staged row (and row+64)
    int aq = tid & 3;           // col quarter: cols aq*16 .. aq*16+15

    f32x4 acc[4][4] = {};
    float fA1 = 0.f, fA2 = 0.f, fB1 = 0.f, fB2 = 0.f;

    for (int k0 = 0; k0 < K; k0 += 64) {
#pragma unroll
        for (int it = 0; it < 4; ++it) {
            int slot = it * 256 + tid;
            int row = slot >> 3;
            int qg = ((slot & 7) ^ (row & 7)) * 8;
            gll16(B + (size_t)row * K + k0 + qg, Bs + (size_t)(it * 256 + wslot) * 8);
        }
        const float4* U0 = (const float4*)(u0 + k0 + aq * 16);
        const float4* U1 = (const float4*)(u1 + k0 + aq * 16);
        float4 ua0 = U0[0], ua1 = U0[1], ua2 = U0[2], ua3 = U0[3];
        float4 va0 = U1[0], va1 = U1[1], va2 = U1[2], va3 = U1[3];
#pragma unroll
        for (int rr = 0; rr < 2; ++rr) {
            int row = ar + rr * 64;
            int ga = bm + row; if (ga > M - 1) ga = M - 1;
            const float4* src = (const float4*)(X + (size_t)ga * K + k0 + aq * 16);
            float4 x0 = src[0], x1 = src[1], x2 = src[2], x3 = src[3];
            float s1 = dot4(x0, ua0) + dot4(x1, ua1) + dot4(x2, ua2) + dot4(x3, ua3);
            float s2 = dot4(x0, va0) + dot4(x1, va1) + dot4(x2, va2) + dot4(x3, va3);
            if (rr == 0) { fA1 += s1; fA2 += s2; } else { fB1 += s1; fB2 += s2; }
            uint4 pa, pb;
            pa.x = pack2(x0.x, x0.y); pa.y = pack2(x0.z, x0.w);
            pa.z = pack2(x1.x, x1.y); pa.w = pack2(x1.z, x1.w);
            pb.x = pack2(x2.x, x2.y); pb.y = pack2(x2.z, x2.w);
            pb.z = pack2(x3.x, x3.y); pb.w = pack2(x3.z, x3.w);
            int c0 = (aq * 2) ^ (row & 7);
            int c1 = (aq * 2 + 1) ^ (row & 7);
            *(uint4*)&As[row * 64 + c0 * 8] = pa;
            *(uint4*)&As[row * 64 + c1 * 8] = pb;
        }
        __syncthreads();
#pragma unroll
        for (int ks = 0; ks < 2; ++ks) {
            bf16x8 af[4], bfr[4];
#pragma unroll
            for (int i = 0; i < 4; ++i) {
                int r = wm + i * 16 + lm;
                af[i] = *(const bf16x8*)&As[r * 64 + (((ks * 4 + quad) ^ (r & 7)) * 8)];
            }
#pragma unroll
            for (int j = 0; j < 4; ++j) {
                int r = wn + j * 16 + lm;
                bfr[j] = *(const bf16x8*)&Bs[r * 64 + (((ks * 4 + quad) ^ (r & 7)) * 8)];
            }
#pragma unroll
            for (int i = 0; i < 4; ++i)
#pragma unroll
                for (int j = 0; j < 4; ++j)
                    acc[i][j] = __builtin_amdgcn_mfma_f32_16x16x32_bf16(af[i], bfr[j], acc[i][j], 0, 0, 0);
        }
        __syncthreads();
    }

    fA1 += __shfl_xor(fA1, 1); fA1 += __shfl_xor(fA1, 2);
    fA2 += __shfl_xor(fA2, 1); fA2 += __shfl_xor(fA2, 2);
    fB1 += __shfl_xor(fB1, 1); fB1 += __shfl_xor(fB1, 2);
    fB2 += __shfl_xor(fB2, 1); fB2 += __shfl_xor(fB2, 2);
    if (aq == 0) {
        float c0 = cc[0], c1 = cc[1];
        int r0 = bm + ar;
        if (r0 < M) { f1[r0] = fA1 + c0; f2[r0] = fA2 + c1; }
        int r1 = r0 + 64;
        if (r1 < M) { f1[r1] = fB1 + c0; f2[r1] = fB2 + c1; }
    }

    float bv[4];
#pragma unroll
    for (int j = 0; j < 4; ++j) bv[j] = bp[wn + j * 16 + lm];
#pragma unroll
    for (int i = 0; i < 4; ++i) {
#pragma unroll
        for (int r = 0; r < 4; ++r) {
            int row = bm + wm + i * 16 + quad * 4 + r;
            if (row < M) {
#pragma unroll
                for (int j = 0; j < 4; ++j) {
                    int col = wn + j * 16 + lm;
                    Ph[(size_t)row * 128 + col] = f2b(acc[i][j][r] + bv[j]);
                }
            }
        }
    }
}

#define FMA8(h, wgt) { \
        acc[0] += (wgt) * b2f((ushort)((h).x & 0xffffu)); \
        acc[1] += (wgt) * b2f((ushort)((h).x >> 16)); \
        acc[2] += (wgt) * b2f((ushort)((h).y & 0xffffu)); \
        acc[3] += (wgt) * b2f((ushort)((h).y >> 16)); \
        acc[4] += (wgt) * b2f((ushort)((h).z & 0xffffu)); \
        acc[5] += (wgt) * b2f((ushort)((h).z >> 16)); \
        acc[6] += (wgt) * b2f((ushort)((h).w & 0xffffu)); \
        acc[7] += (wgt) * b2f((ushort)((h).w >> 16)); }

// ---------------- fused attention + SpMM d=128 ----------------
// Per row r: e_j = exp(sigmoid(a_s[j]*(fin1[r]+fin2[col_j]))); acc = sum e_j*H[col_j];
// out = acc/sum(e) + bias. Stores unnormalized e -> attOut and 1/sum -> rsOut for the
// decoder's plain spmm reuse. Lanes 0..7 of each 16-lane group own edge j+lane of each
// 8-edge batch; weights broadcast to the group via __shfl.
__global__ __launch_bounds__(256) void spmm_att(const int* __restrict__ rp,
                                                const int* __restrict__ col_s,
                                                const float* __restrict__ a_s,
                                                const float* __restrict__ fin1,
                                                const float* __restrict__ fin2,
                                                float* __restrict__ attOut,
                                                float* __restrict__ rsOut,
                                                const ushort* __restrict__ H,
                                                const float* __restrict__ bias,
                                                const float* __restrict__ va,
                                                const float* __restrict__ vb,
                                                float* __restrict__ g1,
                                                float* __restrict__ g2,
                                                ushort* __restrict__ Oh,
                                                float* __restrict__ Of, int N) {
    int r = blockIdx.x * 16 + (threadIdx.x >> 4);
    if (r >= N) return;
    int lane = threadIdx.x & 15;
    int kl = lane & 7;
    int gb = threadIdx.x & 48;          // 16-lane group base within wave
    int beg = rp[r], end = rp[r + 1];
    float fr = fin1[r];
    float ssum = 0.f;
    float acc[8] = {0.f, 0.f, 0.f, 0.f, 0.f, 0.f, 0.f, 0.f};
    const uint4* H4 = (const uint4*)H;
    int j = beg;
    for (; j + 8 <= end; j += 8) {
        // lanes 0..7 (8..15 duplicate) compute e for edge j+kl
        int   cL = col_s[j + kl];
        float aL = a_s[j + kl];
        float xL = aL * (fr + fin2[cL]);
        float eL = __expf(1.f / (1.f + __expf(-xL)));
        if (lane < 8) { attOut[j + lane] = eL; ssum += eL; }
        float w0 = __shfl(eL, gb + 0), w1 = __shfl(eL, gb + 1);
        float w2 = __shfl(eL, gb + 2), w3 = __shfl(eL, gb + 3);
        float w4 = __shfl(eL, gb + 4), w5 = __shfl(eL, gb + 5);
        float w6 = __shfl(eL, gb + 6), w7 = __shfl(eL, gb + 7);
        int c0 = col_s[j],     c1 = col_s[j + 1], c2 = col_s[j + 2], c3 = col_s[j + 3];
        int c4 = col_s[j + 4], c5 = col_s[j + 5], c6 = col_s[j + 6], c7 = col_s[j + 7];
        uint4 h0 = H4[(size_t)c0 * 16 + lane];
        uint4 h1 = H4[(size_t)c1 * 16 + lane];
        uint4 h2 = H4[(size_t)c2 * 16 + lane];
        uint4 h3 = H4[(size_t)c3 * 16 + lane];
        uint4 h4 = H4[(size_t)c4 * 16 + lane];
        uint4 h5 = H4[(size_t)c5 * 16 + lane];
        uint4 h6 = H4[(size_t)c6 * 16 + lane];
        uint4 h7 = H4[(size_t)c7 * 16 + lane];
        FMA8(h0, w0) FMA8(h1, w1) FMA8(h2, w2) FMA8(h3, w3)
        FMA8(h4, w4) FMA8(h5, w5) FMA8(h6, w6) FMA8(h7, w7)
    }
    int rem = end - j;
    if (rem > 0) {
        bool valid = kl < rem;
        int   cL = col_s[valid ? j + kl : beg];
        float aL = valid ? a_s[j + kl] : 0.f;
        float xL = aL * (fr + fin2[cL]);
        float eL = valid ? __expf(1.f / (1.f + __expf(-xL))) : 0.f;
        if (lane < 8 && valid) { attOut[j + lane] = eL; ssum += eL; }
        for (int k = 0; k < rem; ++k) {
            float wk = __shfl(eL, gb + k);
            int ck = col_s[j + k];
            uint4 hk = H4[(size_t)ck * 16 + lane];
            FMA8(hk, wk)
        }
    }
    // row-sum reduce over the 16-lane group (lanes 8..15 hold 0)
    ssum += __shfl_xor(ssum, 1);
    ssum += __shfl_xor(ssum, 2);
    ssum += __shfl_xor(ssum, 4);
    ssum += __shfl_xor(ssum, 8);
    float rsv = (end > beg) ? 1.f / ssum : 0.f;
    if (lane == 0) rsOut[r] = rsv;
#pragma unroll
    for (int k = 0; k < 8; ++k) acc[k] *= rsv;
    if (bias) {
        const float4* b4 = (const float4*)(bias + lane * 8);
        float4 ba = b4[0], bb = b4[1];
        acc[0] += ba.x; acc[1] += ba.y; acc[2] += ba.z; acc[3] += ba.w;
        acc[4] += bb.x; acc[5] += bb.y; acc[6] += bb.z; acc[7] += bb.w;
    }
    if (va) {
        const float4* a4 = (const float4*)(va + lane * 8);
        const float4* c4 = (const float4*)(vb + lane * 8);
        float4 va0 = a4[0], va1 = a4[1], vb0 = c4[0], vb1 = c4[1];
        float p1 = acc[0] * va0.x + acc[1] * va0.y + acc[2] * va0.z + acc[3] * va0.w
                 + acc[4] * va1.x + acc[5] * va1.y + acc[6] * va1.z + acc[7] * va1.w;
        float p2 = acc[0] * vb0.x + acc[1] * vb0.y + acc[2] * vb0.z + acc[3] * vb0.w
                 + acc[4] * vb1.x + acc[5] * vb1.y + acc[6] * vb1.z + acc[7] * vb1.w;
#pragma unroll
        for (int off = 8; off > 0; off >>= 1) {
            p1 += __shfl_xor(p1, off);
            p2 += __shfl_xor(p2, off);
        }
        if (lane == 0) { g1[r] = p1; g2[r] = p2; }
    }
    if (Oh) {
        uint4 o;
        o.x = (uint32_t)f2b(acc[0]) | ((uint32_t)f2b(acc[1]) << 16);
        o.y = (uint32_t)f2b(acc[2]) | ((uint32_t)f2b(acc[3]) << 16);
        o.z = (uint32_t)f2b(acc[4]) | ((uint32_t)f2b(acc[5]) << 16);
        o.w = (uint32_t)f2b(acc[6]) | ((uint32_t)f2b(acc[7]) << 16);
        ((uint4*)Oh)[(size_t)r * 16 + lane] = o;
    }
    if (Of) {
        float4* O4 = (float4*)Of;
        O4[(size_t)r * 32 + lane * 2]     = make_float4(acc[0], acc[1], acc[2], acc[3]);
        O4[(size_t)r * 32 + lane * 2 + 1] = make_float4(acc[4], acc[5], acc[6], acc[7]);
    }
}

// ---------------- plain SpMM d=128 (stored att/rs) ----------------
__global__ __launch_bounds__(256) void spmm128(const int* __restrict__ rp,
                                               const int* __restrict__ col_s,
                                               const float* __restrict__ att,
                                               const float* __restrict__ rs,
                                               const ushort* __restrict__ H,
                                               ushort* __restrict__ Oh, int N) {
    int r = blockIdx.x * 16 + (threadIdx.x >> 4);
    if (r >= N) return;
    int lane = threadIdx.x & 15;
    int beg = rp[r], end = rp[r + 1];
    float acc[8] = {0.f, 0.f, 0.f, 0.f, 0.f, 0.f, 0.f, 0.f};
    const uint4* H4 = (const uint4*)H;
    int j = beg;
    for (; j + 8 <= end; j += 8) {
        int c0 = col_s[j],     c1 = col_s[j + 1], c2 = col_s[j + 2], c3 = col_s[j + 3];
        int c4 = col_s[j + 4], c5 = col_s[j + 5], c6 = col_s[j + 6], c7 = col_s[j + 7];
        float w0 = att[j],     w1 = att[j + 1], w2 = att[j + 2], w3 = att[j + 3];
        float w4 = att[j + 4], w5 = att[j + 5], w6 = att[j + 6], w7 = att[j + 7];
        uint4 h0 = H4[(size_t)c0 * 16 + lane];
        uint4 h1 = H4[(size_t)c1 * 16 + lane];
        uint4 h2 = H4[(size_t)c2 * 16 + lane];
        uint4 h3 = H4[(size_t)c3 * 16 + lane];
        uint4 h4 = H4[(size_t)c4 * 16 + lane];
        uint4 h5 = H4[(size_t)c5 * 16 + lane];
        uint4 h6 = H4[(size_t)c6 * 16 + lane];
        uint4 h7 = H4[(size_t)c7 * 16 + lane];
        FMA8(h0, w0) FMA8(h1, w1) FMA8(h2, w2) FMA8(h3, w3)
        FMA8(h4, w4) FMA8(h5, w5) FMA8(h6, w6) FMA8(h7, w7)
    }
    for (; j < end; ++j) {
        uint4 h = H4[(size_t)col_s[j] * 16 + lane];
        float w0 = att[j];
        FMA8(h, w0)
    }
    float rsv = rs[r];
#pragma unroll
    for (int k = 0; k < 8; ++k) acc[k] *= rsv;
    uint4 o;
    o.x = (uint32_t)f2b(acc[0]) | ((uint32_t)f2b(acc[1]) << 16);
    o.y = (uint32_t)f2b(acc[2]) | ((uint32_t)f2b(acc[3]) << 16);
    o.z = (uint32_t)f2b(acc[4]) | ((uint32_t)f2b(acc[5]) << 16);
    o.w = (uint32_t)f2b(acc[6]) | ((uint32_t)f2b(acc[7]) << 16);
    ((uint4*)Oh)[(size_t)r * 16 + lane] = o;
}
#undef FMA8

// ---------------- driver ----------------
// Algebra (all ops linear; softmax rows sum to 1 so bias commutes through spmm):
//   f1/f2 (layer0) = X.(W0^T v) + b0.v       (fused into P-GEMM; M0 never materialized)
//   Wp = W1@W0 [128,512], bp = W1 b0
//   P  = X@Wp^T + bp                         [N,128]  (== M0@W1^T)
//   M1 = spmm(att0, P) + b1                  [N,128]  (att0 computed inline)
//   H2 = spmm(att1, M1)                      [N,128]  (att1 computed inline; final_H)
//   out = spmm(att0, spmm(att1, H2)) @ Wp    [N,512]
extern "C" void kernel_launch(void* const* d_in, const int* in_sizes, int n_in,
                              void* d_out, int out_size, void* d_ws, size_t ws_size,
                              hipStream_t stream) {
    const float* X    = (const float*)d_in[0];
    const int*   erow = (const int*)d_in[1];
    const int*   ecol = (const int*)d_in[2];
    const float* aval = (const float*)d_in[3];
    const float* W0   = (const float*)d_in[4];
    const float* b0   = (const float*)d_in[5];
    const float* W1   = (const float*)d_in[6];
    const float* b1   = (const float*)d_in[7];
    const float* v00  = (const float*)d_in[8];
    const float* v01  = (const float*)d_in[9];
    const float* v10  = (const float*)d_in[10];
    const float* v11  = (const float*)d_in[11];

    const int D0 = 512, D1 = 256, D2 = 128;
    const int N = in_sizes[0] / D0;
    const int E = in_sizes[1];
    const int NB = (N + 127) / 128;
    float* out = (float*)d_out;

    char* ws = (char*)d_ws;
    size_t off = 0;
    auto alloc = [&](size_t bytes) {
        char* p = ws + off;
        off += (bytes + 255) & ~(size_t)255;
        return p;
    };
    ushort* Ph   = (ushort*)alloc((size_t)N * D2 * 2);  // P / S1
    ushort* M1h  = (ushort*)alloc((size_t)N * D2 * 2);
    ushort* H2h  = (ushort*)alloc((size_t)N * D2 * 2);
    ushort* S0h  = (ushort*)alloc((size_t)N * D2 * 2);
    ushort* W1h  = (ushort*)alloc((size_t)D2 * D1 * 2); // [128,256]
    ushort* Wt0h = (ushort*)alloc((size_t)D0 * D1 * 2); // W0^T [512,256]
    ushort* Wph  = (ushort*)alloc((size_t)D2 * D0 * 2); // Wp = W1@W0 [128,512]
    ushort* WfTh = (ushort*)alloc((size_t)D0 * D2 * 2); // Wp^T [512,128]
    float* att0  = (float*)alloc((size_t)E * 4);
    float* att1  = (float*)alloc((size_t)E * 4);
    float* a_s   = (float*)alloc((size_t)E * 4);
    float* f1    = (float*)alloc((size_t)N * 4);
    float* f2    = (float*)alloc((size_t)N * 4);
    float* g1    = (float*)alloc((size_t)N * 4);
    float* g2    = (float*)alloc((size_t)N * 4);
    float* rs0   = (float*)alloc((size_t)N * 4);
    float* rs1   = (float*)alloc((size_t)N * 4);
    float* u0    = (float*)alloc(512 * 4);
    float* u1    = (float*)alloc(512 * 4);
    float* bp    = (float*)alloc(128 * 4);
    float* cc    = (float*)alloc(2 * 4);
    int* rp      = (int*)alloc(((size_t)N + 1) * 4);
    int* col_s   = (int*)alloc((size_t)E * 4);
    uint2* tmp   = (uint2*)alloc((size_t)E * 8);
    int* bhist   = (int*)alloc(512 * 4);
    int* boff    = (int*)alloc(513 * 4);
    int* gcur    = (int*)alloc(512 * 4);

    // ---- CSR build ----
    hipMemsetAsync(bhist, 0, 512 * sizeof(int), stream);
    hist_kernel<<<256, 256, 0, stream>>>(erow, bhist, E, NB);
    scan512<<<1, 512, 0, stream>>>(bhist, boff, gcur, rp, NB, E, N);
    binpass<<<(E + 4095) / 4096, 256, 0, stream>>>(erow, ecol, aval, gcur, tmp, E, NB);
    bucketpass<<<NB, 256, 0, stream>>>(tmp, boff, rp, col_s, a_s, N);

    // ---- weight prep (one dispatch) ----
    prep_all<<<145, 256, 0, stream>>>(W0, W1, b0, v00, v01, W1h, Wt0h, u0, u1, bp, cc);

    // ---- fused weight: Wp[128,512] = W1@W0 = gemm_nt(W1h, Wt0h); also emit Wp^T ----
    gemm_bf16<<<dim3(4, 1), 256, 0, stream>>>(W1h, Wt0h, nullptr, nullptr, Wph, WfTh,
                                              D2, D1, D0);

    const int gy = (N + 127) / 128;
    const int sgrid = (N + 15) / 16;

    // ---- encoder ----
    // P = X@Wp^T + bp, fused f1/f2 = X.u0/u1 + cc (fp32)
    gemm_xp<<<dim3(1, gy), 256, 0, stream>>>(X, Wph, bp, u0, u1, cc, Ph, f1, f2, N, D0);
    // M1 = spmm(att0, P) + b1 with att0 computed inline; fused g1/g2 = M1 . v10/v11
    spmm_att<<<sgrid, 256, 0, stream>>>(rp, col_s, a_s, f1, f2, att0, rs0,
                                        Ph, b1, v10, v11, g1, g2, M1h, nullptr, N);
    // H2 = spmm(att1, M1) with att1 computed inline; bf16 + fp32 out-tail
    spmm_att<<<sgrid, 256, 0, stream>>>(rp, col_s, a_s, g1, g2, att1, rs1,
                                        M1h, nullptr, nullptr, nullptr, nullptr, nullptr,
                                        H2h, out + (size_t)N * D0, N);

    // ---- decoder (fully commuted; stored att/rs reuse) ----
    spmm128<<<sgrid, 256, 0, stream>>>(rp, col_s, att1, rs1, H2h, Ph, N);   // S1
    spmm128<<<sgrid, 256, 0, stream>>>(rp, col_s, att0, rs0, Ph, S0h, N);   // S0
    gemm_bf16<<<dim3(D0 / 128, gy), 256, 0, stream>>>(S0h, WfTh, nullptr, out, nullptr,
                                                      nullptr, N, D2, D0);
}